// Round 4
// baseline (2120.494 us; speedup 1.0000x reference)
//
#include <hip/hip_runtime.h>

typedef __bf16 bf16;
typedef __bf16 bf16x8 __attribute__((ext_vector_type(8)));
typedef float floatx4 __attribute__((ext_vector_type(4)));

#define BB 8
#define LL 2048
#define DD 2048
#define NHH 32
#define HDD 64

// ---------------- weight transpose + cast: WT[n][k] = (bf16)W[k][n] ----------------
__global__ __launch_bounds__(256) void transpose1(const float* __restrict__ src,
                                                  bf16* __restrict__ dst)
{
  __shared__ float tile[64][65];
  const int t = threadIdx.x;
  const int col = t & 63, rw = t >> 6;
  const int bx = blockIdx.x * 64, by = blockIdx.y * 64;
  for (int i = rw; i < 64; i += 4)
    tile[i][col] = src[(size_t)(by + i) * DD + bx + col];
  __syncthreads();
  for (int i = rw; i < 64; i += 4)
    dst[(size_t)(bx + i) * DD + by + col] = (bf16)tile[col][i];
}

// ---------------- GEMM: C[16384][2048] = A x B, B given transposed bf16 (BT[n][k]) ----
// AIDX==0: A is fp32 row-major [row][d] (cast to bf16 while staging).
// AIDX==1: A is bf16 stored [b][h][l][f] (QKV layout).
// EPI==0:  C fp32 row-major.   EPI==1: C bf16 scattered to QKV layout (b,h,l,f).
template<int AIDX, int EPI>
__global__ __launch_bounds__(256) void gemm_bt(const void* __restrict__ Av,
    const bf16* __restrict__ BT, void* __restrict__ Cv)
{
  constexpr int Kd = 2048;
  __shared__ alignas(16) bf16 As[128][72];  // pitch 144B: 16B aligned, breaks 128B-stride conflicts
  __shared__ alignas(16) bf16 Bs[128][72];
  const int t = threadIdx.x;
  const int bn = blockIdx.x, bm = blockIdx.y;
  const int wave = t >> 6, lane = t & 63;
  const int m16 = lane & 15, quad = lane >> 4;
  floatx4 acc[2][8] = {};
  const int srow = t >> 3;            // 0..31
  const int schunk = (t & 7) * 8;     // k-subchunk of 8 elements
  const bf16* Bb = BT + (size_t)(bn * 128) * Kd;

  for (int k0 = 0; k0 < Kd; k0 += 64) {
    for (int i = 0; i < 4; ++i) {
      int r = srow + 32 * i;
      if (AIDX == 0) {
        const float* asrc = (const float*)Av + (size_t)(bm * 128 + r) * Kd + k0 + schunk;
        floatx4 f0 = *(const floatx4*)asrc;
        floatx4 f1 = *(const floatx4*)(asrc + 4);
        bf16x8 v;
        v[0] = (bf16)f0[0]; v[1] = (bf16)f0[1]; v[2] = (bf16)f0[2]; v[3] = (bf16)f0[3];
        v[4] = (bf16)f1[0]; v[5] = (bf16)f1[1]; v[6] = (bf16)f1[2]; v[7] = (bf16)f1[3];
        *(bf16x8*)&As[r][schunk] = v;
      } else {
        int R = bm * 128 + r;
        int b = R >> 11, l = R & 2047;
        int dcol = k0 + schunk;                 // multiple of 8, within one head
        int h = dcol >> 6, f = dcol & 63;
        const bf16* asrc = (const bf16*)Av + (((size_t)(b * NHH + h) * LL + l) * HDD + f);
        *(bf16x8*)&As[r][schunk] = *(const bf16x8*)asrc;
      }
      *(bf16x8*)&Bs[r][schunk] = *(const bf16x8*)(Bb + (size_t)r * Kd + k0 + schunk);
    }
    __syncthreads();
    for (int kk = 0; kk < 2; ++kk) {
      bf16x8 af[2], bfr[8];
      for (int mt = 0; mt < 2; ++mt)
        af[mt] = *(const bf16x8*)&As[wave * 32 + mt * 16 + m16][kk * 32 + quad * 8];
      for (int nt = 0; nt < 8; ++nt)
        bfr[nt] = *(const bf16x8*)&Bs[nt * 16 + m16][kk * 32 + quad * 8];
      for (int mt = 0; mt < 2; ++mt)
        for (int nt = 0; nt < 8; ++nt)
          acc[mt][nt] = __builtin_amdgcn_mfma_f32_16x16x32_bf16(af[mt], bfr[nt], acc[mt][nt], 0, 0, 0);
    }
    __syncthreads();
  }

  for (int mt = 0; mt < 2; ++mt)
    for (int nt = 0; nt < 8; ++nt)
      for (int rg = 0; rg < 4; ++rg) {
        int row = bm * 128 + wave * 32 + mt * 16 + quad * 4 + rg;
        int col = bn * 128 + nt * 16 + m16;
        if (EPI == 0) {
          ((float*)Cv)[(size_t)row * DD + col] = acc[mt][nt][rg];
        } else {
          int b = row >> 11, l = row & 2047;
          int h = col >> 6, f = col & 63;
          ((bf16*)Cv)[((size_t)(b * NHH + h) * LL + l) * HDD + f] = (bf16)acc[mt][nt][rg];
        }
      }
}

// ---------------- RoPE (interleaved pairs), in-place on bf16 Q and K ----------------
__global__ __launch_bounds__(256) void rope_qk(bf16* __restrict__ Q, bf16* __restrict__ Kt)
{
  bf16* X = blockIdx.y ? Kt : Q;
  unsigned p = blockIdx.x * 256u + threadIdx.x;   // pair index < 2^24
  int i = p & 31;
  int l = (p >> 5) & 2047;
  int bh = p >> 16;
  float invf = expf(-(float)i * 0.28782313662425573f);  // ln(10000)/32
  float th = (float)l * invf;
  float cs = cosf(th), sn = sinf(th);
  size_t off = (size_t)bh * (LL * HDD) + (size_t)l * HDD + 2 * i;
  float x0 = (float)X[off], x1 = (float)X[off + 1];
  X[off]     = (bf16)(x0 * cs - x1 * sn);
  X[off + 1] = (bf16)(x1 * cs + x0 * sn);
}

// ---------------- TTT scan: one block per (b,h), 128 sequential chunks ----------------
// O aliases Q (QKV layout; no __restrict__ on these two): chunk c of Q is consumed
// into LDS (stage 1) before the same chunk is overwritten (stage 5); barriers between.
__global__ __launch_bounds__(256) void ttt_scan(
    const bf16* Q, const bf16* __restrict__ Kx,
    const bf16* __restrict__ V, const float* __restrict__ W1g,
    const float* __restrict__ b1g, const float* __restrict__ gw,
    const float* __restrict__ gb, bf16* O)
{
  const int bh = blockIdx.x, h = bh & 31;
  const int t = threadIdx.x;
  __shared__ float W1s[HDD * HDD];           // [f][g], pitch 64
  __shared__ float xqs[16 * 68], xks[16 * 68], xvs[16 * 68];  // pitch 68 breaks conflicts
  __shared__ float Z1s[16 * 68], grads[16 * 68];
  __shared__ float attns[16 * 17];
  __shared__ float b1s[64], gsh[64], bbh[64];

  for (int i = t; i < 4096; i += 256) W1s[i] = W1g[(size_t)h * 4096 + i];
  if (t < 64) {
    b1s[t] = b1g[h * 64 + t];
    gsh[t] = gw[h * 64 + t];
    bbh[t] = gb[h * 64 + t];
  }
  __syncthreads();

  const size_t qkvbase = (size_t)bh * (LL * HDD);
  const int g64 = t & 63, kb = t >> 6;     // matmul mapping: col g64, rows kb+4i
  const int kr = t >> 4, sr = t & 15;      // row-reduce mapping: row kr, segment sr
  const int f0 = sr * 4;

  for (int c = 0; c < 128; ++c) {
    // stage 1: load chunk (16x64 each of q,k,v)
    {
      const size_t base = qkvbase + (size_t)c * (16 * 64);
      int e = t * 4;
      int k = e >> 6, f = e & 63;
      for (int j = 0; j < 4; ++j) {
        xqs[k * 68 + f + j] = (float)Q[base + e + j];
        xks[k * 68 + f + j] = (float)Kx[base + e + j];
        xvs[k * 68 + f + j] = (float)V[base + e + j];
      }
    }
    __syncthreads();
    // stage 2: Z1 = xk @ W1 + b1
    {
      float a0 = b1s[g64], a1 = a0, a2 = a0, a3 = a0;
      for (int f = 0; f < 64; ++f) {
        float w = W1s[f * 64 + g64];
        a0 += xks[(kb     ) * 68 + f] * w;
        a1 += xks[(kb +  4) * 68 + f] * w;
        a2 += xks[(kb +  8) * 68 + f] * w;
        a3 += xks[(kb + 12) * 68 + f] * w;
      }
      Z1s[(kb     ) * 68 + g64] = a0;
      Z1s[(kb +  4) * 68 + g64] = a1;
      Z1s[(kb +  8) * 68 + g64] = a2;
      Z1s[(kb + 12) * 68 + g64] = a3;
    }
    __syncthreads();
    // stage 3: attn (tril(xq xk^T)) + LN fused-l2 backward -> grads
    {
      float ad = 0.f;
      for (int f = 0; f < 64; ++f) ad += xqs[kr * 68 + f] * xks[sr * 68 + f];
      attns[kr * 17 + sr] = (sr <= kr) ? ad : 0.f;

      float z[4], tg[4], sum = 0.f, ssq = 0.f;
      for (int j = 0; j < 4; ++j) {
        z[j]  = Z1s[kr * 68 + f0 + j];
        tg[j] = xvs[kr * 68 + f0 + j] - xks[kr * 68 + f0 + j];
        sum += z[j]; ssq += z[j] * z[j];
      }
      for (int m = 1; m < 16; m <<= 1) { sum += __shfl_xor(sum, m, 64); ssq += __shfl_xor(ssq, m, 64); }
      float mu = sum * (1.f / 64.f);
      float var = ssq * (1.f / 64.f) - mu * mu;
      float rstd = rsqrtf(var + 1e-6f);
      float xh[4], gx[4], s1 = 0.f, s2 = 0.f;
      for (int j = 0; j < 4; ++j) {
        xh[j] = (z[j] - mu) * rstd;
        float go = gsh[f0 + j] * xh[j] + bbh[f0 + j] - tg[j];
        gx[j] = go * gsh[f0 + j];
        s1 += gx[j]; s2 += gx[j] * xh[j];
      }
      for (int m = 1; m < 16; m <<= 1) { s1 += __shfl_xor(s1, m, 64); s2 += __shfl_xor(s2, m, 64); }
      for (int j = 0; j < 4; ++j)
        grads[kr * 68 + f0 + j] = (64.f * gx[j] - s1 - xh[j] * s2) * (rstd * (1.f / 64.f));
    }
    __syncthreads();
    // stage 4: Z1_bar = xq@W1 + b1 - eta_k * sum_{l<=k}(attn+1)*grad ; W1 delta accum
    float del[16];
    float gsum = 0.f;
    {
      float a[4];
      int ks[4] = {kb, kb + 4, kb + 8, kb + 12};
      for (int i = 0; i < 4; ++i) a[i] = b1s[g64];
      for (int f = 0; f < 64; ++f) {
        float w = W1s[f * 64 + g64];
        for (int i = 0; i < 4; ++i) a[i] += xqs[ks[i] * 68 + f] * w;
      }
      for (int i = 0; i < 4; ++i) {
        int k = ks[i];
        float s = 0.f;
        for (int l = 0; l <= k; ++l) s += (attns[k * 17 + l] + 1.f) * grads[l * 68 + g64];
        a[i] -= s / (float)(k + 1);
      }
      for (int i = 0; i < 4; ++i) Z1s[ks[i] * 68 + g64] = a[i];
      for (int j = 0; j < 16; ++j) del[j] = 0.f;
      for (int k = 0; k < 16; ++k) {
        float gr = grads[k * 68 + g64];
        if (kb == 0) gsum += gr;
        for (int j = 0; j < 16; ++j) del[j] += xks[k * 68 + kb + 4 * j] * gr;
      }
    }
    __syncthreads();
    // stage 5: out = xq + LN_fwd(Z1_bar) -> O (aliases Q, QKV layout); W1/b1 update
    {
      float z[4], sum = 0.f, ssq = 0.f;
      for (int j = 0; j < 4; ++j) {
        z[j] = Z1s[kr * 68 + f0 + j];
        sum += z[j]; ssq += z[j] * z[j];
      }
      for (int m = 1; m < 16; m <<= 1) { sum += __shfl_xor(sum, m, 64); ssq += __shfl_xor(ssq, m, 64); }
      float mu = sum * (1.f / 64.f);
      float var = ssq * (1.f / 64.f) - mu * mu;
      float rstd = rsqrtf(var + 1e-6f);
      size_t obase = qkvbase + (size_t)c * (16 * 64) + (size_t)kr * 64 + f0;
      for (int j = 0; j < 4; ++j) {
        float xh = (z[j] - mu) * rstd;
        float ov = xqs[kr * 68 + f0 + j] + gsh[f0 + j] * xh + bbh[f0 + j];
        O[obase + j] = (bf16)ov;
      }
      for (int j = 0; j < 16; ++j)
        W1s[(kb + 4 * j) * 64 + g64] -= (1.f / 16.f) * del[j];
      if (kb == 0) b1s[g64] -= (1.f / 16.f) * gsum;
    }
    __syncthreads();
  }
}

extern "C" void kernel_launch(void* const* d_in, const int* in_sizes, int n_in,
                              void* d_out, int out_size, void* d_ws, size_t ws_size,
                              hipStream_t stream)
{
  const float* X  = (const float*)d_in[0];
  const float* wq = (const float*)d_in[1];
  const float* wk = (const float*)d_in[2];
  const float* wv = (const float*)d_in[3];
  const float* wo = (const float*)d_in[4];
  const float* W1 = (const float*)d_in[5];
  const float* b1 = (const float*)d_in[6];
  const float* gw = (const float*)d_in[7];
  const float* gb = (const float*)d_in[8];

  bf16* ws = (bf16*)d_ws;
  const size_t NEl = (size_t)BB * LL * DD;   // 33,554,432 elems per tensor
  bf16* Q  = ws;                 // also the scan output O (aliased)
  bf16* Kb = ws + NEl;
  bf16* WT = ws + 2 * NEl;       // single 2048x2048 transposed bf16 weight slot, reused
  bf16* Vb = (bf16*)d_out;       // V (bf16, 64 MB) lives in d_out (fp32, 128 MB);
                                 // fully consumed before the final GEMM overwrites d_out.
  // workspace: 2*64MB + 8MB = 136,314,880 bytes

  transpose1<<<dim3(32, 32), 256, 0, stream>>>(wq, WT);
  gemm_bt<0, 1><<<dim3(16, 128), 256, 0, stream>>>(X, WT, Q);
  transpose1<<<dim3(32, 32), 256, 0, stream>>>(wk, WT);
  gemm_bt<0, 1><<<dim3(16, 128), 256, 0, stream>>>(X, WT, Kb);
  transpose1<<<dim3(32, 32), 256, 0, stream>>>(wv, WT);
  gemm_bt<0, 1><<<dim3(16, 128), 256, 0, stream>>>(X, WT, Vb);
  rope_qk<<<dim3(65536, 2), 256, 0, stream>>>(Q, Kb);
  ttt_scan<<<dim3(256), 256, 0, stream>>>(Q, Kb, Vb, W1, b1, gw, gb, Q);
  transpose1<<<dim3(32, 32), 256, 0, stream>>>(wo, WT);
  gemm_bt<1, 0><<<dim3(16, 128), 256, 0, stream>>>(Q, WT, d_out);
}